// Round 1
// baseline (5032.476 us; speedup 1.0000x reference)
//
#include <hip/hip_runtime.h>
#include <math.h>

#define NB 64      // 2N total samples
#define NH 8       // heads
#define ND 256     // per-head dim
#define NS 288     // spatial positions
#define NF 2048    // FDIM
#define HALF_N 32
#define TEMP 50.0f

#define RECON_ELEMS ((size_t)NB * NF * NS)

// ---- workspace layout (floats) ----
#define WS_NORM   0
#define WS_MASK   (NB*NH*NS)                 // 147456
#define WS_CPOS   (2*NB*NH*NS)               // 294912
#define WS_COMASK (3*NB*NH*NS)               // 442368
#define WS_AP     (3*NB*NH*NS + NB*NS)       // 460800
#define WS_AN     (4*NB*NH*NS + NB*NS)       // 608256

__device__ __forceinline__ const float* feat_ptr(const float* fv, const float* ft, int b) {
    return (b < HALF_N) ? fv + (size_t)b * NF * NS : ft + (size_t)(b - HALF_N) * NF * NS;
}

// ---------------- K1: per-(b,h,s) channel L2 norm + min-max mask ----------------
__global__ __launch_bounds__(256) void norm_mask_kernel(
        const float* __restrict__ fv, const float* __restrict__ ft,
        float* __restrict__ normArr, float* __restrict__ maskArr) {
    const int bh = blockIdx.x;            // 0..511
    const int b = bh >> 3, h = bh & 7;
    const float* f = feat_ptr(fv, ft, b) + (size_t)h * ND * NS;
    const int tid = threadIdx.x;          // 256
    __shared__ float smn[256], smx[256];

    const int s1 = tid, s2 = tid + 256;
    float n1 = 0.f, n2 = 0.f;
    for (int d = 0; d < ND; ++d) {
        float v1 = f[d * NS + s1];
        n1 += v1 * v1;
        if (s2 < NS) { float v2 = f[d * NS + s2]; n2 += v2 * v2; }
    }
    n1 = sqrtf(n1);
    float lmn = n1, lmx = n1;
    if (s2 < NS) { n2 = sqrtf(n2); lmn = fminf(lmn, n2); lmx = fmaxf(lmx, n2); }
    normArr[bh * NS + s1] = n1;
    if (s2 < NS) normArr[bh * NS + s2] = n2;

    smn[tid] = lmn; smx[tid] = lmx;
    __syncthreads();
    for (int off = 128; off > 0; off >>= 1) {
        if (tid < off) {
            smn[tid] = fminf(smn[tid], smn[tid + off]);
            smx[tid] = fmaxf(smx[tid], smx[tid + off]);
        }
        __syncthreads();
    }
    const float mn = smn[0];
    const float inv = 1.0f / (smx[0] - mn + 1e-12f);
    maskArr[bh * NS + s1] = (n1 - mn) * inv;
    if (s2 < NS) maskArr[bh * NS + s2] = (n2 - mn) * inv;
}

// ---------------- K2: fused attention (sim -> softmax -> PV -> recon/dist) ----------------
// grid: (18 s-blocks, 512 bh, 2 pass)   block: 256
// LDS: sim[16][292] | buf{q[256][16], k[32][128]} / v[32][260] | rkn[288] maskk[288] rqn[16] maskq[16] rl[16]
#define SIM_PITCH 292
#define V_PITCH 260
#define SMEM_FLOATS (16*SIM_PITCH + 8320 + 288 + 288 + 16 + 16 + 16)

__global__ __launch_bounds__(256, 2) void attn_kernel(
        const float* __restrict__ fv, const float* __restrict__ ft,
        const int* __restrict__ pos_idx, const int* __restrict__ neg_idx,
        const float* __restrict__ normArr, const float* __restrict__ maskArr,
        float* __restrict__ out_recon, float* __restrict__ c_pos,
        float* __restrict__ ap_part, float* __restrict__ an_part) {
    const int sblk = blockIdx.x;     // 0..17
    const int bh   = blockIdx.y;     // 0..511
    const int pass = blockIdx.z;     // 0=pos, 1=neg
    const int b = bh >> 3, h = bh & 7;
    const int p = (pass == 0) ? pos_idx[b] : neg_idx[b];
    const int s0 = sblk * 16;
    const float* fq = feat_ptr(fv, ft, b) + (size_t)h * ND * NS;
    const float* fk = feat_ptr(fv, ft, p) + (size_t)h * ND * NS;

    __shared__ float smem[SMEM_FLOATS];
    float* sim   = smem;                       // 16*292 = 4672
    float* buf   = smem + 16 * SIM_PITCH;      // 8320 floats
    float* q     = buf;                        // [256][16]
    float* kc    = buf + 4096;                 // [32][128]
    float* vv    = buf;                        // [32][260] (reuses q+kc after sim)
    float* rkn   = smem + 16 * SIM_PITCH + 8320;
    float* maskk = rkn + NS;
    float* rqn   = maskk + NS;
    float* maskq = rqn + 16;
    float* rl    = maskq + 16;

    const int tid = threadIdx.x;
    // stage per-row/col scalars
    for (int t = tid; t < NS; t += 256) {
        rkn[t]   = 1.0f / fmaxf(normArr[(p * NH + h) * NS + t], 1e-12f);
        maskk[t] = maskArr[(p * NH + h) * NS + t];
    }
    if (tid < 16) {
        rqn[tid]   = 1.0f / fmaxf(normArr[bh * NS + s0 + tid], 1e-12f);
        maskq[tid] = maskArr[bh * NS + s0 + tid];
    }
    // stage Q tile (raw): q[d][si]
    {
        const int si = tid & 15;
        const int dr = tid >> 4;           // 0..15
        for (int i = 0; i < 16; ++i) {
            const int d = dr + i * 16;
            q[d * 16 + si] = fq[d * NS + s0 + si];
        }
    }

    const int ty = tid >> 6;       // 0..3  (== wave id)
    const int tx = tid & 63;       // lane
    const int si0 = ty * 4;

    // ---- sim phase: raw dot products, t-chunks of 128 ----
    for (int tc = 0; tc < NS; tc += 128) {
        float acc[4][2] = {{0.f,0.f},{0.f,0.f},{0.f,0.f},{0.f,0.f}};
        for (int dc = 0; dc < ND; dc += 32) {
            __syncthreads();
            {   // load kc[32][128]
                const int tj = tid & 127;
                const int dd0 = tid >> 7;
                const int t = tc + tj;
                for (int dd = dd0; dd < 32; dd += 2)
                    kc[dd * 128 + tj] = (t < NS) ? fk[(dc + dd) * NS + t] : 0.0f;
            }
            __syncthreads();
            const int tj0 = tx * 2;
            #pragma unroll
            for (int dd = 0; dd < 32; ++dd) {
                const float4 q4 = *(const float4*)&q[(dc + dd) * 16 + si0];
                const float2 k2 = *(const float2*)&kc[dd * 128 + tj0];
                acc[0][0] += q4.x * k2.x; acc[0][1] += q4.x * k2.y;
                acc[1][0] += q4.y * k2.x; acc[1][1] += q4.y * k2.y;
                acc[2][0] += q4.z * k2.x; acc[2][1] += q4.z * k2.y;
                acc[3][0] += q4.w * k2.x; acc[3][1] += q4.w * k2.y;
            }
        }
        const int tj0 = tx * 2;
        #pragma unroll
        for (int i = 0; i < 4; ++i)
            #pragma unroll
            for (int jj = 0; jj < 2; ++jj) {
                const int t = tc + tj0 + jj;
                if (t < NS) sim[(si0 + i) * SIM_PITCH + t] = acc[i][jj];
            }
    }
    __syncthreads();

    // ---- softmax (rows of 288), plus comask row-sum ----
    {
        const int row = tid >> 4;        // 0..15
        const int l16 = tid & 15;
        const float scale = TEMP * rqn[row];
        float vals[18];
        float m = -1e30f;
        #pragma unroll
        for (int k = 0; k < 18; ++k) {
            const int t = l16 + k * 16;
            const float lg = scale * sim[row * SIM_PITCH + t] * rkn[t];
            vals[k] = lg;
            m = fmaxf(m, lg);
        }
        #pragma unroll
        for (int off = 8; off > 0; off >>= 1) m = fmaxf(m, __shfl_xor(m, off, 16));
        float l = 0.f, cm = 0.f;
        #pragma unroll
        for (int k = 0; k < 18; ++k) {
            const int t = l16 + k * 16;
            const float pv = __expf(vals[k] - m);
            sim[row * SIM_PITCH + t] = pv;   // unnormalized P
            l += pv;
            cm += pv * maskk[t];
        }
        #pragma unroll
        for (int off = 8; off > 0; off >>= 1) {
            l += __shfl_xor(l, off, 16);
            cm += __shfl_xor(cm, off, 16);
        }
        if (l16 == 0) {
            rl[row] = 1.0f / l;
            if (pass == 0) c_pos[bh * NS + s0 + row] = maskq[row] * cm / l;
        }
    }
    __syncthreads();

    // ---- PV phase: out[si][d] = (sum_t P*V) / l ----
    float acc[4][4];
    #pragma unroll
    for (int i = 0; i < 4; ++i)
        #pragma unroll
        for (int j = 0; j < 4; ++j) acc[i][j] = 0.f;
    const int d0 = tx * 4;
    for (int tc = 0; tc < NS; tc += 32) {
        __syncthreads();
        {   // load vv[32][260]
            const int t_in = tid & 31;
            const int drow = tid >> 5;     // 0..7
            const int tg = tc + t_in;
            for (int db = 0; db < ND; db += 8)
                vv[t_in * V_PITCH + db + drow] = fk[(db + drow) * NS + tg];
        }
        __syncthreads();
        #pragma unroll
        for (int tt = 0; tt < 32; ++tt) {
            const float4 v4 = *(const float4*)&vv[tt * V_PITCH + d0];
            const float p0 = sim[(si0 + 0) * SIM_PITCH + tc + tt];
            const float p1 = sim[(si0 + 1) * SIM_PITCH + tc + tt];
            const float p2 = sim[(si0 + 2) * SIM_PITCH + tc + tt];
            const float p3 = sim[(si0 + 3) * SIM_PITCH + tc + tt];
            acc[0][0] += p0 * v4.x; acc[0][1] += p0 * v4.y; acc[0][2] += p0 * v4.z; acc[0][3] += p0 * v4.w;
            acc[1][0] += p1 * v4.x; acc[1][1] += p1 * v4.y; acc[1][2] += p1 * v4.z; acc[1][3] += p1 * v4.w;
            acc[2][0] += p2 * v4.x; acc[2][1] += p2 * v4.y; acc[2][2] += p2 * v4.z; acc[2][3] += p2 * v4.w;
            acc[3][0] += p3 * v4.x; acc[3][1] += p3 * v4.y; acc[3][2] += p3 * v4.z; acc[3][3] += p3 * v4.w;
        }
    }

    // ---- epilogue: recon + squared-diff partials ----
    {
        float rls[4], mq[4];
        #pragma unroll
        for (int i = 0; i < 4; ++i) { rls[i] = rl[si0 + i]; mq[i] = maskq[si0 + i]; }
        float sqsum[4] = {0.f, 0.f, 0.f, 0.f};
        #pragma unroll
        for (int j = 0; j < 4; ++j) {
            const int d = d0 + j;
            const float4 f4 = *(const float4*)&fq[d * NS + s0 + si0];
            const float fvv[4] = {f4.x, f4.y, f4.z, f4.w};
            float rec[4];
            #pragma unroll
            for (int i = 0; i < 4; ++i) {
                const float o = acc[i][j] * rls[i];
                rec[i] = fvv[i] + mq[i] * (o - fvv[i]);
                const float diff = mq[i] * (fvv[i] - o) + 1e-6f;
                sqsum[i] += diff * diff;
            }
            if (pass == 0) {
                float4 r4;
                r4.x = rec[0]; r4.y = rec[1]; r4.z = rec[2]; r4.w = rec[3];
                *(float4*)&out_recon[((size_t)b * NF + (size_t)h * ND + d) * NS + s0 + si0] = r4;
            }
        }
        #pragma unroll
        for (int off = 32; off > 0; off >>= 1)
            #pragma unroll
            for (int i = 0; i < 4; ++i) sqsum[i] += __shfl_xor(sqsum[i], off, 64);
        if (tx == 0) {
            float* dst = (pass == 0) ? ap_part : an_part;
            #pragma unroll
            for (int i = 0; i < 4; ++i) dst[bh * NS + s0 + si0 + i] = sqsum[i];
        }
    }
}

// ---------------- K3: comask = minmax(norm_over_heads(c_pos)) ----------------
__global__ __launch_bounds__(256) void comask_kernel(
        const float* __restrict__ c_pos, float* __restrict__ comask) {
    const int b = blockIdx.x;
    const int tid = threadIdx.x;
    __shared__ float smn[256], smx[256];
    const int s1 = tid, s2 = tid + 256;
    float c1 = 0.f, c2 = 0.f;
    for (int h = 0; h < NH; ++h) {
        const float v = c_pos[(b * NH + h) * NS + s1];
        c1 += v * v;
        if (s2 < NS) { const float w = c_pos[(b * NH + h) * NS + s2]; c2 += w * w; }
    }
    c1 = sqrtf(c1);
    float lmn = c1, lmx = c1;
    if (s2 < NS) { c2 = sqrtf(c2); lmn = fminf(lmn, c2); lmx = fmaxf(lmx, c2); }
    smn[tid] = lmn; smx[tid] = lmx;
    __syncthreads();
    for (int off = 128; off > 0; off >>= 1) {
        if (tid < off) {
            smn[tid] = fminf(smn[tid], smn[tid + off]);
            smx[tid] = fmaxf(smx[tid], smx[tid + off]);
        }
        __syncthreads();
    }
    const float mn = smn[0];
    const float inv = 1.0f / (smx[0] - mn + 1e-12f);
    comask[b * NS + s1] = (c1 - mn) * inv;
    if (s2 < NS) comask[b * NS + s2] = (c2 - mn) * inv;
}

// ---------------- K4: triplet loss reduction ----------------
__global__ __launch_bounds__(256) void loss_kernel(
        const float* __restrict__ comask, const float* __restrict__ ap_part,
        const float* __restrict__ an_part, float* __restrict__ out_loss) {
    const int tid = threadIdx.x;
    __shared__ float sred[256];
    float partial = 0.f;
    for (int s = tid; s < NS; s += 256) {
        float ca = 0.f, ta = 0.f;
        for (int b = 0; b < NB; ++b) {
            ca += comask[b * NS + s];
            float ap = 0.f, an = 0.f;
            for (int h = 0; h < NH; ++h) {
                ap += ap_part[(b * NH + h) * NS + s];
                an += an_part[(b * NH + h) * NS + s];
            }
            ta += fmaxf(sqrtf(ap) - sqrtf(an) + 0.3f, 0.0f);
        }
        partial += ca * ta;
    }
    sred[tid] = partial;
    __syncthreads();
    for (int off = 128; off > 0; off >>= 1) {
        if (tid < off) sred[tid] += sred[tid + off];
        __syncthreads();
    }
    if (tid == 0) out_loss[0] = sred[0] * (1.0f / ((float)NB * (float)NB * (float)NS));
}

extern "C" void kernel_launch(void* const* d_in, const int* in_sizes, int n_in,
                              void* d_out, int out_size, void* d_ws, size_t ws_size,
                              hipStream_t stream) {
    const float* fv = (const float*)d_in[0];
    const float* ft = (const float*)d_in[1];
    const int* pos  = (const int*)d_in[2];
    const int* neg  = (const int*)d_in[3];
    float* out = (float*)d_out;
    float* ws  = (float*)d_ws;

    float* normArr = ws + WS_NORM;
    float* maskArr = ws + WS_MASK;
    float* c_pos   = ws + WS_CPOS;
    float* comask  = ws + WS_COMASK;
    float* ap      = ws + WS_AP;
    float* an      = ws + WS_AN;

    norm_mask_kernel<<<dim3(NB * NH), dim3(256), 0, stream>>>(fv, ft, normArr, maskArr);
    attn_kernel<<<dim3(NS / 16, NB * NH, 2), dim3(256), 0, stream>>>(
        fv, ft, pos, neg, normArr, maskArr, out, c_pos, ap, an);
    comask_kernel<<<dim3(NB), dim3(256), 0, stream>>>(c_pos, comask);
    loss_kernel<<<dim3(1), dim3(256), 0, stream>>>(comask, ap, an, out + RECON_ELEMS);
}

// Round 6
// 999.128 us; speedup vs baseline: 5.0369x; 5.0369x over previous
//
#include <hip/hip_runtime.h>
#include <math.h>

#define NB 64      // 2N total samples
#define NH 8       // heads
#define ND 256     // per-head dim
#define NS 288     // spatial positions
#define NF 2048    // FDIM
#define HALF_N 32

#define RECON_ELEMS ((size_t)NB * NF * NS)

// ---- workspace layout (floats) ----
#define WS_NORM   0
#define WS_MASK   (NB*NH*NS)                 // 147456
#define WS_CPOS   (2*NB*NH*NS)               // 294912
#define WS_COMASK (3*NB*NH*NS)               // 442368
#define WS_AP     (3*NB*NH*NS + NB*NS)       // 460800
#define WS_AN     (4*NB*NH*NS + NB*NS)       // 608256
#define WS_PROD   (5*NB*NH*NS + NB*NS)       // 755712

typedef short bf16x8 __attribute__((ext_vector_type(8)));
typedef short bf16x4 __attribute__((ext_vector_type(4)));
typedef float f32x4  __attribute__((ext_vector_type(4)));

__device__ __forceinline__ unsigned short f2bf(float f) {
    unsigned int u = __float_as_uint(f);
    return (unsigned short)((u + 0x7fffu + ((u >> 16) & 1u)) >> 16);
}

__device__ __forceinline__ const float* feat_ptr(const float* fv, const float* ft, int b) {
    return (b < HALF_N) ? fv + (size_t)b * NF * NS : ft + (size_t)(b - HALF_N) * NF * NS;
}

// ---------------- K1: per-(b,h,s) channel L2 norm + min-max mask ----------------
__global__ __launch_bounds__(256) void norm_mask_kernel(
        const float* __restrict__ fv, const float* __restrict__ ft,
        float* __restrict__ normArr, float* __restrict__ maskArr) {
    const int bh = blockIdx.x;            // 0..511
    const int b = bh >> 3, h = bh & 7;
    const float* f = feat_ptr(fv, ft, b) + (size_t)h * ND * NS;
    const int tid = threadIdx.x;          // 256
    __shared__ float smn[256], smx[256];

    const int s1 = tid, s2 = tid + 256;
    float n1 = 0.f, n2 = 0.f;
    for (int d = 0; d < ND; ++d) {
        float v1 = f[d * NS + s1];
        n1 += v1 * v1;
        if (s2 < NS) { float v2 = f[d * NS + s2]; n2 += v2 * v2; }
    }
    n1 = sqrtf(n1);
    float lmn = n1, lmx = n1;
    if (s2 < NS) { n2 = sqrtf(n2); lmn = fminf(lmn, n2); lmx = fmaxf(lmx, n2); }
    normArr[bh * NS + s1] = n1;
    if (s2 < NS) normArr[bh * NS + s2] = n2;

    smn[tid] = lmn; smx[tid] = lmx;
    __syncthreads();
    for (int off = 128; off > 0; off >>= 1) {
        if (tid < off) {
            smn[tid] = fminf(smn[tid], smn[tid + off]);
            smx[tid] = fmaxf(smx[tid], smx[tid + off]);
        }
        __syncthreads();
    }
    const float mn = smn[0];
    const float inv = 1.0f / (smx[0] - mn + 1e-12f);
    maskArr[bh * NS + s1] = (n1 - mn) * inv;
    if (s2 < NS) maskArr[bh * NS + s2] = (n2 - mn) * inv;
}

// ---------------- K2: fused MFMA attention ----------------
// grid (3 sblk, 512 bh, 2 pass) x 384 threads (6 waves, each owns 16 queries)
// S^T = mfma(A=K, B=Q); P^T stays in C-layout regs; O^T = mfma(A=V^T, B=P^T).
#define DPT 264   // ldsKT pitch (bf16 elems): row stride 528B, 16B-aligned
#define TCP 36    // ldsKN pitch (bf16 elems): row stride 72B, 8B-aligned

__global__ __launch_bounds__(384, 2) void attn_kernel(
        const float* __restrict__ fv, const float* __restrict__ ft,
        const int* __restrict__ pos_idx, const int* __restrict__ neg_idx,
        const float* __restrict__ normArr, const float* __restrict__ maskArr,
        float* __restrict__ out_recon, float* __restrict__ c_pos,
        float* __restrict__ ap_part, float* __restrict__ an_part) {
    const int sblk = blockIdx.x;     // 0..2 (96 queries each)
    const int bh   = blockIdx.y;     // 0..511
    const int pass = blockIdx.z;     // 0=pos, 1=neg
    const int b = bh >> 3, h = bh & 7;
    const int p = (pass == 0) ? pos_idx[b] : neg_idx[b];
    const float* fq = feat_ptr(fv, ft, b) + (size_t)h * ND * NS;
    const float* fk = feat_ptr(fv, ft, p) + (size_t)h * ND * NS;

    __shared__ __align__(16) unsigned short ldsKT[32 * DPT];  // K^T chunk [t][d]
    __shared__ __align__(16) unsigned short ldsKN[256 * TCP]; // K chunk [d][t]
    __shared__ float ldsRKN[NS];
    __shared__ float ldsMK[NS];

    const int tid = threadIdx.x;
    const int a   = tid & 15;          // m/n index within MFMA tile
    const int g   = (tid >> 4) & 3;    // k-group within wave
    const int qt  = tid >> 6;          // wave id = q-tile 0..5
    const int sq  = sblk * 96 + qt * 16 + a;   // this lane's query s

    // stage per-t scalars (1/||k||, mask_k)
    for (int i = tid; i < NS; i += 384) {
        ldsRKN[i] = 1.0f / fmaxf(normArr[(p * NH + h) * NS + i], 1e-12f);
        ldsMK[i]  = maskArr[(p * NH + h) * NS + i];
    }
    const float rq = 1.0f / fmaxf(normArr[bh * NS + sq], 1e-12f);
    const float mq = maskArr[bh * NS + sq];

    // Q fragments (B-operand, n=sq): qf[ks][j] = Q[d = 32ks+8g+j][sq]
    bf16x8 qf[8];
    #pragma unroll
    for (int ks = 0; ks < 8; ++ks) {
        #pragma unroll
        for (int j = 0; j < 8; ++j)
            qf[ks][j] = (short)f2bf(fq[(32 * ks + 8 * g + j) * NS + sq]);
    }

    f32x4 accO[16];
    #pragma unroll
    for (int i = 0; i < 16; ++i) accO[i] = (f32x4){0.f, 0.f, 0.f, 0.f};
    float lsum = 0.f, csum = 0.f;

    const int t2 = tid & 15;   // staging: t-pair index
    const int dg = tid >> 4;   // staging: d start 0..23

    for (int tc = 0; tc < NS; tc += 32) {
        __syncthreads();
        // stage K chunk: one global read feeds both LDS layouts
        for (int d = dg; d < 256; d += 24) {
            const float2 v = *(const float2*)&fk[d * NS + tc + 2 * t2];
            const unsigned int b0 = f2bf(v.x), b1 = f2bf(v.y);
            *(unsigned int*)&ldsKN[d * TCP + 2 * t2] = b0 | (b1 << 16);
            ldsKT[(2 * t2) * DPT + d]     = (unsigned short)b0;
            ldsKT[(2 * t2 + 1) * DPT + d] = (unsigned short)b1;
        }
        __syncthreads();

        // ---- QK^T: S^T[t][q], t in two 16-tiles ----
        f32x4 sacc0 = {0.f,0.f,0.f,0.f}, sacc1 = {0.f,0.f,0.f,0.f};
        #pragma unroll
        for (int ks = 0; ks < 8; ++ks) {
            const bf16x8 ka0 = *(const bf16x8*)&ldsKT[a * DPT + 32 * ks + 8 * g];
            const bf16x8 ka1 = *(const bf16x8*)&ldsKT[(a + 16) * DPT + 32 * ks + 8 * g];
            sacc0 = __builtin_amdgcn_mfma_f32_16x16x32_bf16(ka0, qf[ks], sacc0, 0, 0, 0);
            sacc1 = __builtin_amdgcn_mfma_f32_16x16x32_bf16(ka1, qf[ks], sacc1, 0, 0, 0);
        }

        // ---- softmax terms: P = exp(50 * dot * rq * rkn[t]) (no max needed) ----
        bf16x8 pf;
        #pragma unroll
        for (int r = 0; r < 4; ++r) {
            const int t0 = tc + 4 * g + r;
            const float p0 = __expf(50.0f * sacc0[r] * rq * ldsRKN[t0]);
            lsum += p0; csum += p0 * ldsMK[t0];
            pf[r] = (short)f2bf(p0);
            const int t1 = tc + 16 + 4 * g + r;
            const float p1 = __expf(50.0f * sacc1[r] * rq * ldsRKN[t1]);
            lsum += p1; csum += p1 * ldsMK[t1];
            pf[4 + r] = (short)f2bf(p1);
        }

        // ---- PV: O^T[d][q] += V^T-frag x P^T-frag ----
        #pragma unroll
        for (int dt = 0; dt < 16; ++dt) {
            const int row = dt * 16 + a;
            const bf16x4 lo = *(const bf16x4*)&ldsKN[row * TCP + 4 * g];
            const bf16x4 hi = *(const bf16x4*)&ldsKN[row * TCP + 16 + 4 * g];
            bf16x8 va;
            va[0]=lo[0]; va[1]=lo[1]; va[2]=lo[2]; va[3]=lo[3];
            va[4]=hi[0]; va[5]=hi[1]; va[6]=hi[2]; va[7]=hi[3];
            accO[dt] = __builtin_amdgcn_mfma_f32_16x16x32_bf16(va, pf, accO[dt], 0, 0, 0);
        }
    }

    // reduce l, cm across the 4 k-groups (lanes sharing a)
    lsum += __shfl_xor(lsum, 16); lsum += __shfl_xor(lsum, 32);
    csum += __shfl_xor(csum, 16); csum += __shfl_xor(csum, 32);
    const float linv = 1.0f / lsum;
    if (pass == 0 && (tid & 63) < 16)
        c_pos[bh * NS + sq] = mq * csum * linv;

    // epilogue: recon + squared-diff partials
    float ss = 0.f;
    #pragma unroll
    for (int dt = 0; dt < 16; ++dt) {
        #pragma unroll
        for (int r = 0; r < 4; ++r) {
            const int d = dt * 16 + 4 * g + r;
            const float o = accO[dt][r] * linv;
            const float f = fq[d * NS + sq];
            const float diff = mq * (f - o) + 1e-6f;
            ss += diff * diff;
            if (pass == 0)
                out_recon[((size_t)b * NF + (size_t)h * ND + d) * NS + sq] = f + mq * (o - f);
        }
    }
    ss += __shfl_xor(ss, 16); ss += __shfl_xor(ss, 32);
    if ((tid & 63) < 16) {
        float* dst = (pass == 0) ? ap_part : an_part;
        dst[bh * NS + sq] = ss;
    }
}

// ---------------- K3: comask = minmax(norm_over_heads(c_pos)) ----------------
__global__ __launch_bounds__(256) void comask_kernel(
        const float* __restrict__ c_pos, float* __restrict__ comask) {
    const int b = blockIdx.x;
    const int tid = threadIdx.x;
    __shared__ float smn[256], smx[256];
    const int s1 = tid, s2 = tid + 256;
    float c1 = 0.f, c2 = 0.f;
    for (int h = 0; h < NH; ++h) {
        const float v = c_pos[(b * NH + h) * NS + s1];
        c1 += v * v;
        if (s2 < NS) { const float w = c_pos[(b * NH + h) * NS + s2]; c2 += w * w; }
    }
    c1 = sqrtf(c1);
    float lmn = c1, lmx = c1;
    if (s2 < NS) { c2 = sqrtf(c2); lmn = fminf(lmn, c2); lmx = fmaxf(lmx, c2); }
    smn[tid] = lmn; smx[tid] = lmx;
    __syncthreads();
    for (int off = 128; off > 0; off >>= 1) {
        if (tid < off) {
            smn[tid] = fminf(smn[tid], smn[tid + off]);
            smx[tid] = fmaxf(smx[tid], smx[tid + off]);
        }
        __syncthreads();
    }
    const float mn = smn[0];
    const float inv = 1.0f / (smx[0] - mn + 1e-12f);
    comask[b * NS + s1] = (c1 - mn) * inv;
    if (s2 < NS) comask[b * NS + s2] = (c2 - mn) * inv;
}

// ---------------- K4a: per-s triplet/comask partial products ----------------
__global__ __launch_bounds__(64) void loss_partial(
        const float* __restrict__ comask, const float* __restrict__ ap_part,
        const float* __restrict__ an_part, float* __restrict__ prod) {
    const int s = blockIdx.x;       // 0..287
    const int bb = threadIdx.x;     // 0..63 = b
    float sap = 0.f, san = 0.f;
    for (int hh = 0; hh < NH; ++hh) {
        sap += ap_part[(bb * NH + hh) * NS + s];
        san += an_part[(bb * NH + hh) * NS + s];
    }
    float trip = fmaxf(sqrtf(sap) - sqrtf(san) + 0.3f, 0.0f);
    float cm = comask[bb * NS + s];
    #pragma unroll
    for (int off = 32; off > 0; off >>= 1) {
        trip += __shfl_xor(trip, off);
        cm   += __shfl_xor(cm, off);
    }
    if (bb == 0) prod[s] = trip * cm;
}

// ---------------- K4b: final loss ----------------
__global__ __launch_bounds__(64) void loss_final(
        const float* __restrict__ prod, float* __restrict__ out_loss) {
    const int tid = threadIdx.x;
    float sum = 0.f;
    for (int i = tid; i < NS; i += 64) sum += prod[i];
    #pragma unroll
    for (int off = 32; off > 0; off >>= 1) sum += __shfl_xor(sum, off);
    if (tid == 0) out_loss[0] = sum * (1.0f / ((float)NB * (float)NB * (float)NS));
}

extern "C" void kernel_launch(void* const* d_in, const int* in_sizes, int n_in,
                              void* d_out, int out_size, void* d_ws, size_t ws_size,
                              hipStream_t stream) {
    const float* fv = (const float*)d_in[0];
    const float* ft = (const float*)d_in[1];
    const int* pos  = (const int*)d_in[2];
    const int* neg  = (const int*)d_in[3];
    float* out = (float*)d_out;
    float* ws  = (float*)d_ws;

    float* normArr = ws + WS_NORM;
    float* maskArr = ws + WS_MASK;
    float* c_pos   = ws + WS_CPOS;
    float* comask  = ws + WS_COMASK;
    float* ap      = ws + WS_AP;
    float* an      = ws + WS_AN;
    float* prod    = ws + WS_PROD;

    norm_mask_kernel<<<dim3(NB * NH), dim3(256), 0, stream>>>(fv, ft, normArr, maskArr);
    attn_kernel<<<dim3(3, NB * NH, 2), dim3(384), 0, stream>>>(
        fv, ft, pos, neg, normArr, maskArr, out, c_pos, ap, an);
    comask_kernel<<<dim3(NB), dim3(256), 0, stream>>>(c_pos, comask);
    loss_partial<<<dim3(NS), dim3(64), 0, stream>>>(comask, ap, an, prod);
    loss_final<<<dim3(1), dim3(64), 0, stream>>>(prod, out + RECON_ELEMS);
}

// Round 8
// 876.562 us; speedup vs baseline: 5.7411x; 1.1398x over previous
//
#include <hip/hip_runtime.h>
#include <math.h>

#define NB 64      // 2N total samples
#define NH 8       // heads
#define ND 256     // per-head dim
#define NS 288     // spatial positions
#define NF 2048    // FDIM
#define HALF_N 32

#define RECON_ELEMS ((size_t)NB * NF * NS)

// ---- fp32 workspace layout (floats) ----
#define WS_NORM   0
#define WS_MASK   (NB*NH*NS)                 // 147456
#define WS_CPOS   (2*NB*NH*NS)               // 294912
#define WS_COMASK (3*NB*NH*NS)               // 442368
#define WS_AP     (3*NB*NH*NS + NB*NS)       // 460800
#define WS_AN     (4*NB*NH*NS + NB*NS)       // 608256
#define WS_PROD   (5*NB*NH*NS + NB*NS)       // 755712
// bf16 region (fast path): starts at 4MB byte offset
#define WS_BF_OFF ((size_t)4 << 20)
#define BF_ONE    ((size_t)NB * NH * NS * ND * 2)   // 75,497,472 B per layout

typedef short bf16x8 __attribute__((ext_vector_type(8)));
typedef short bf16x4 __attribute__((ext_vector_type(4)));
typedef float f32x4  __attribute__((ext_vector_type(4)));

__device__ __forceinline__ unsigned short f2bf(float f) {
    unsigned int u = __float_as_uint(f);
    return (unsigned short)((u + 0x7fffu + ((u >> 16) & 1u)) >> 16);
}

__device__ __forceinline__ const float* feat_ptr(const float* fv, const float* ft, int b) {
    return (b < HALF_N) ? fv + (size_t)b * NF * NS : ft + (size_t)(b - HALF_N) * NF * NS;
}

// ================= FAST PATH =================

// ---- C1: norms + mask + featKN ([bh][d][s] bf16) ----
__global__ __launch_bounds__(256) void convKN_norm_mask(
        const float* __restrict__ fv, const float* __restrict__ ft,
        float* __restrict__ normArr, float* __restrict__ maskArr,
        unsigned short* __restrict__ featKN) {
    const int bh = blockIdx.x;            // 0..511
    const int b = bh >> 3, h = bh & 7;
    const float* f = feat_ptr(fv, ft, b) + (size_t)h * ND * NS;
    unsigned short* kn = featKN + (size_t)bh * ND * NS;
    const int tid = threadIdx.x;
    __shared__ float smn[256], smx[256];

    const int s1 = tid, s2 = tid + 256;
    float n1 = 0.f, n2 = 0.f;
    for (int d = 0; d < ND; ++d) {
        float v1 = f[d * NS + s1];
        n1 += v1 * v1;
        kn[d * NS + s1] = f2bf(v1);
        if (s2 < NS) {
            float v2 = f[d * NS + s2];
            n2 += v2 * v2;
            kn[d * NS + s2] = f2bf(v2);
        }
    }
    n1 = sqrtf(n1);
    float lmn = n1, lmx = n1;
    if (s2 < NS) { n2 = sqrtf(n2); lmn = fminf(lmn, n2); lmx = fmaxf(lmx, n2); }
    normArr[bh * NS + s1] = n1;
    if (s2 < NS) normArr[bh * NS + s2] = n2;

    smn[tid] = lmn; smx[tid] = lmx;
    __syncthreads();
    for (int off = 128; off > 0; off >>= 1) {
        if (tid < off) {
            smn[tid] = fminf(smn[tid], smn[tid + off]);
            smx[tid] = fmaxf(smx[tid], smx[tid + off]);
        }
        __syncthreads();
    }
    const float mn = smn[0];
    const float inv = 1.0f / (smx[0] - mn + 1e-12f);
    maskArr[bh * NS + s1] = (n1 - mn) * inv;
    if (s2 < NS) maskArr[bh * NS + s2] = (n2 - mn) * inv;
}

// ---- C2: featKT ([bh][s][d] bf16) via LDS tile transpose ----
__global__ __launch_bounds__(256) void convKT(
        const float* __restrict__ fv, const float* __restrict__ ft,
        unsigned short* __restrict__ featKT) {
    const int s0 = blockIdx.x * 32;       // 0..8 tiles
    const int bh = blockIdx.y;            // 0..511
    const int b = bh >> 3, h = bh & 7;
    const float* f = feat_ptr(fv, ft, b) + (size_t)h * ND * NS;
    const int tid = threadIdx.x;
    __shared__ unsigned short tile[256 * 33];

    const int sc = tid & 31;
    for (int d = tid >> 5; d < ND; d += 8)
        tile[d * 33 + sc] = f2bf(f[(size_t)d * NS + s0 + sc]);
    __syncthreads();

    for (int u = tid; u < 1024; u += 256) {
        const int s_r = u >> 5;           // 0..31
        const int du  = u & 31;           // 0..31 (8 d's each)
        bf16x8 v;
        #pragma unroll
        for (int j = 0; j < 8; ++j) v[j] = tile[(du * 8 + j) * 33 + s_r];
        *(bf16x8*)&featKT[((size_t)bh * NS + s0 + s_r) * ND + du * 8] = v;
    }
}

// ---- K2 fast: fused MFMA attention reading precomputed bf16 ----
#define DPT 264   // ldsKT pitch (bf16 elems)
#define TCP 36    // ldsKN pitch (bf16 elems)

__global__ __launch_bounds__(384, 2) void attn_fast(
        const unsigned short* __restrict__ featKT,
        const unsigned short* __restrict__ featKN,
        const float* __restrict__ fv, const float* __restrict__ ft,
        const int* __restrict__ pos_idx, const int* __restrict__ neg_idx,
        const float* __restrict__ normArr, const float* __restrict__ maskArr,
        float* __restrict__ out_recon, float* __restrict__ c_pos,
        float* __restrict__ ap_part, float* __restrict__ an_part) {
    const int sblk = blockIdx.x;     // 0..2
    const int bh   = blockIdx.y;     // 0..511
    const int pass = blockIdx.z;     // 0=pos, 1=neg
    const int b = bh >> 3, h = bh & 7;
    const int p = (pass == 0) ? pos_idx[b] : neg_idx[b];
    const int bhk = p * NH + h;
    const float* fq = feat_ptr(fv, ft, b) + (size_t)h * ND * NS;

    __shared__ __align__(16) unsigned short ldsKT[32 * DPT];
    __shared__ __align__(16) unsigned short ldsKN[256 * TCP];
    __shared__ float ldsRKN[NS];
    __shared__ float ldsMK[NS];

    const int tid = threadIdx.x;
    const int a   = tid & 15;
    const int g   = (tid >> 4) & 3;
    const int qt  = tid >> 6;
    const int sq  = sblk * 96 + qt * 16 + a;

    for (int i = tid; i < NS; i += 384) {
        ldsRKN[i] = 1.0f / fmaxf(normArr[bhk * NS + i], 1e-12f);
        ldsMK[i]  = maskArr[bhk * NS + i];
    }
    const float rq = 1.0f / fmaxf(normArr[bh * NS + sq], 1e-12f);
    const float mq = maskArr[bh * NS + sq];

    // Q fragments: contiguous-d b128 loads from featKT
    bf16x8 qf[8];
    {
        const unsigned short* qrow = featKT + ((size_t)bh * NS + sq) * ND;
        #pragma unroll
        for (int ks = 0; ks < 8; ++ks)
            qf[ks] = *(const bf16x8*)&qrow[32 * ks + 8 * g];
    }

    f32x4 accO[16];
    #pragma unroll
    for (int i = 0; i < 16; ++i) accO[i] = (f32x4){0.f, 0.f, 0.f, 0.f};
    float lsum = 0.f, csum = 0.f;

    const unsigned short* kT = featKT + (size_t)bhk * NS * ND;   // [t][d]
    const unsigned short* kN = featKN + (size_t)bhk * ND * NS;   // [d][t]

    // staging registers (T14 prefetch: issue next chunk's loads before compute)
    bf16x8 rT[3], rN[3];
    #define ISSUE(tc_) {                                                        \
        _Pragma("unroll")                                                       \
        for (int k = 0; k < 3; ++k) {                                           \
            const int i = tid + 384 * k;                                        \
            if (i < 1024) {                                                     \
                rT[k] = *(const bf16x8*)&kT[(size_t)((tc_) + (i >> 5)) * ND + (i & 31) * 8]; \
                rN[k] = *(const bf16x8*)&kN[(size_t)(i >> 2) * NS + (tc_) + (i & 3) * 8];    \
            }                                                                   \
        }                                                                       \
    }

    ISSUE(0);
    for (int tc = 0; tc < NS; tc += 32) {
        __syncthreads();
        // write staged regs to LDS
        #pragma unroll
        for (int k = 0; k < 3; ++k) {
            const int i = tid + 384 * k;
            if (i < 1024) {
                *(bf16x8*)&ldsKT[(i >> 5) * DPT + (i & 31) * 8] = rT[k];
                bf16x4 lo, hi;
                lo[0]=rN[k][0]; lo[1]=rN[k][1]; lo[2]=rN[k][2]; lo[3]=rN[k][3];
                hi[0]=rN[k][4]; hi[1]=rN[k][5]; hi[2]=rN[k][6]; hi[3]=rN[k][7];
                *(bf16x4*)&ldsKN[(i >> 2) * TCP + (i & 3) * 8]     = lo;
                *(bf16x4*)&ldsKN[(i >> 2) * TCP + (i & 3) * 8 + 4] = hi;
            }
        }
        if (tc + 32 < NS) ISSUE(tc + 32);
        __syncthreads();

        // ---- QK^T: S^T[t][q] ----
        f32x4 sacc0 = {0.f,0.f,0.f,0.f}, sacc1 = {0.f,0.f,0.f,0.f};
        #pragma unroll
        for (int ks = 0; ks < 8; ++ks) {
            const bf16x8 ka0 = *(const bf16x8*)&ldsKT[a * DPT + 32 * ks + 8 * g];
            const bf16x8 ka1 = *(const bf16x8*)&ldsKT[(a + 16) * DPT + 32 * ks + 8 * g];
            sacc0 = __builtin_amdgcn_mfma_f32_16x16x32_bf16(ka0, qf[ks], sacc0, 0, 0, 0);
            sacc1 = __builtin_amdgcn_mfma_f32_16x16x32_bf16(ka1, qf[ks], sacc1, 0, 0, 0);
        }

        // ---- softmax terms (max-free) ----
        bf16x8 pf;
        #pragma unroll
        for (int r = 0; r < 4; ++r) {
            const int t0 = tc + 4 * g + r;
            const float p0 = __expf(50.0f * sacc0[r] * rq * ldsRKN[t0]);
            lsum += p0; csum += p0 * ldsMK[t0];
            pf[r] = (short)f2bf(p0);
            const int t1 = tc + 16 + 4 * g + r;
            const float p1 = __expf(50.0f * sacc1[r] * rq * ldsRKN[t1]);
            lsum += p1; csum += p1 * ldsMK[t1];
            pf[4 + r] = (short)f2bf(p1);
        }

        // ---- PV: O^T[d][q] ----
        #pragma unroll
        for (int dt = 0; dt < 16; ++dt) {
            const int row = dt * 16 + a;
            const bf16x4 lo = *(const bf16x4*)&ldsKN[row * TCP + 4 * g];
            const bf16x4 hi = *(const bf16x4*)&ldsKN[row * TCP + 16 + 4 * g];
            bf16x8 va;
            va[0]=lo[0]; va[1]=lo[1]; va[2]=lo[2]; va[3]=lo[3];
            va[4]=hi[0]; va[5]=hi[1]; va[6]=hi[2]; va[7]=hi[3];
            accO[dt] = __builtin_amdgcn_mfma_f32_16x16x32_bf16(va, pf, accO[dt], 0, 0, 0);
        }
    }
    #undef ISSUE

    lsum += __shfl_xor(lsum, 16); lsum += __shfl_xor(lsum, 32);
    csum += __shfl_xor(csum, 16); csum += __shfl_xor(csum, 32);
    const float linv = 1.0f / lsum;
    if (pass == 0 && (tid & 63) < 16)
        c_pos[bh * NS + sq] = mq * csum * linv;

    float ss = 0.f;
    #pragma unroll
    for (int dt = 0; dt < 16; ++dt) {
        #pragma unroll
        for (int r = 0; r < 4; ++r) {
            const int d = dt * 16 + 4 * g + r;
            const float o = accO[dt][r] * linv;
            const float f = fq[d * NS + sq];
            const float diff = mq * (f - o) + 1e-6f;
            ss += diff * diff;
            if (pass == 0)
                out_recon[((size_t)b * NF + (size_t)h * ND + d) * NS + sq] = f + mq * (o - f);
        }
    }
    ss += __shfl_xor(ss, 16); ss += __shfl_xor(ss, 32);
    if ((tid & 63) < 16) {
        float* dst = (pass == 0) ? ap_part : an_part;
        dst[bh * NS + sq] = ss;
    }
}

// ================= SLOW PATH (fallback, proven) =================

__global__ __launch_bounds__(256) void norm_mask_kernel(
        const float* __restrict__ fv, const float* __restrict__ ft,
        float* __restrict__ normArr, float* __restrict__ maskArr) {
    const int bh = blockIdx.x;
    const int b = bh >> 3, h = bh & 7;
    const float* f = feat_ptr(fv, ft, b) + (size_t)h * ND * NS;
    const int tid = threadIdx.x;
    __shared__ float smn[256], smx[256];

    const int s1 = tid, s2 = tid + 256;
    float n1 = 0.f, n2 = 0.f;
    for (int d = 0; d < ND; ++d) {
        float v1 = f[d * NS + s1];
        n1 += v1 * v1;
        if (s2 < NS) { float v2 = f[d * NS + s2]; n2 += v2 * v2; }
    }
    n1 = sqrtf(n1);
    float lmn = n1, lmx = n1;
    if (s2 < NS) { n2 = sqrtf(n2); lmn = fminf(lmn, n2); lmx = fmaxf(lmx, n2); }
    normArr[bh * NS + s1] = n1;
    if (s2 < NS) normArr[bh * NS + s2] = n2;

    smn[tid] = lmn; smx[tid] = lmx;
    __syncthreads();
    for (int off = 128; off > 0; off >>= 1) {
        if (tid < off) {
            smn[tid] = fminf(smn[tid], smn[tid + off]);
            smx[tid] = fmaxf(smx[tid], smx[tid + off]);
        }
        __syncthreads();
    }
    const float mn = smn[0];
    const float inv = 1.0f / (smx[0] - mn + 1e-12f);
    maskArr[bh * NS + s1] = (n1 - mn) * inv;
    if (s2 < NS) maskArr[bh * NS + s2] = (n2 - mn) * inv;
}

__global__ __launch_bounds__(384, 2) void attn_kernel(
        const float* __restrict__ fv, const float* __restrict__ ft,
        const int* __restrict__ pos_idx, const int* __restrict__ neg_idx,
        const float* __restrict__ normArr, const float* __restrict__ maskArr,
        float* __restrict__ out_recon, float* __restrict__ c_pos,
        float* __restrict__ ap_part, float* __restrict__ an_part) {
    const int sblk = blockIdx.x;
    const int bh   = blockIdx.y;
    const int pass = blockIdx.z;
    const int b = bh >> 3, h = bh & 7;
    const int p = (pass == 0) ? pos_idx[b] : neg_idx[b];
    const float* fq = feat_ptr(fv, ft, b) + (size_t)h * ND * NS;
    const float* fk = feat_ptr(fv, ft, p) + (size_t)h * ND * NS;

    __shared__ __align__(16) unsigned short ldsKT[32 * DPT];
    __shared__ __align__(16) unsigned short ldsKN[256 * TCP];
    __shared__ float ldsRKN[NS];
    __shared__ float ldsMK[NS];

    const int tid = threadIdx.x;
    const int a   = tid & 15;
    const int g   = (tid >> 4) & 3;
    const int qt  = tid >> 6;
    const int sq  = sblk * 96 + qt * 16 + a;

    for (int i = tid; i < NS; i += 384) {
        ldsRKN[i] = 1.0f / fmaxf(normArr[(p * NH + h) * NS + i], 1e-12f);
        ldsMK[i]  = maskArr[(p * NH + h) * NS + i];
    }
    const float rq = 1.0f / fmaxf(normArr[bh * NS + sq], 1e-12f);
    const float mq = maskArr[bh * NS + sq];

    bf16x8 qf[8];
    #pragma unroll
    for (int ks = 0; ks < 8; ++ks) {
        #pragma unroll
        for (int j = 0; j < 8; ++j)
            qf[ks][j] = (short)f2bf(fq[(32 * ks + 8 * g + j) * NS + sq]);
    }

    f32x4 accO[16];
    #pragma unroll
    for (int i = 0; i < 16; ++i) accO[i] = (f32x4){0.f, 0.f, 0.f, 0.f};
    float lsum = 0.f, csum = 0.f;

    const int t2 = tid & 15;
    const int dg = tid >> 4;

    for (int tc = 0; tc < NS; tc += 32) {
        __syncthreads();
        for (int d = dg; d < 256; d += 24) {
            const float2 v = *(const float2*)&fk[d * NS + tc + 2 * t2];
            const unsigned int b0 = f2bf(v.x), b1 = f2bf(v.y);
            *(unsigned int*)&ldsKN[d * TCP + 2 * t2] = b0 | (b1 << 16);
            ldsKT[(2 * t2) * DPT + d]     = (unsigned short)b0;
            ldsKT[(2 * t2 + 1) * DPT + d] = (unsigned short)b1;
        }
        __syncthreads();

        f32x4 sacc0 = {0.f,0.f,0.f,0.f}, sacc1 = {0.f,0.f,0.f,0.f};
        #pragma unroll
        for (int ks = 0; ks < 8; ++ks) {
            const bf16x8 ka0 = *(const bf16x8*)&ldsKT[a * DPT + 32 * ks + 8 * g];
            const bf16x8 ka1 = *(const bf16x8*)&ldsKT[(a + 16) * DPT + 32 * ks + 8 * g];
            sacc0 = __builtin_amdgcn_mfma_f32_16x16x32_bf16(ka0, qf[ks], sacc0, 0, 0, 0);
            sacc1 = __builtin_amdgcn_mfma_f32_16x16x32_bf16(ka1, qf[ks], sacc1, 0, 0, 0);
        }

        bf16x8 pf;
        #pragma unroll
        for (int r = 0; r < 4; ++r) {
            const int t0 = tc + 4 * g + r;
            const float p0 = __expf(50.0f * sacc0[r] * rq * ldsRKN[t0]);
            lsum += p0; csum += p0 * ldsMK[t0];
            pf[r] = (short)f2bf(p0);
            const int t1 = tc + 16 + 4 * g + r;
            const float p1 = __expf(50.0f * sacc1[r] * rq * ldsRKN[t1]);
            lsum += p1; csum += p1 * ldsMK[t1];
            pf[4 + r] = (short)f2bf(p1);
        }

        #pragma unroll
        for (int dt = 0; dt < 16; ++dt) {
            const int row = dt * 16 + a;
            const bf16x4 lo = *(const bf16x4*)&ldsKN[row * TCP + 4 * g];
            const bf16x4 hi = *(const bf16x4*)&ldsKN[row * TCP + 16 + 4 * g];
            bf16x8 va;
            va[0]=lo[0]; va[1]=lo[1]; va[2]=lo[2]; va[3]=lo[3];
            va[4]=hi[0]; va[5]=hi[1]; va[6]=hi[2]; va[7]=hi[3];
            accO[dt] = __builtin_amdgcn_mfma_f32_16x16x32_bf16(va, pf, accO[dt], 0, 0, 0);
        }
    }

    lsum += __shfl_xor(lsum, 16); lsum += __shfl_xor(lsum, 32);
    csum += __shfl_xor(csum, 16); csum += __shfl_xor(csum, 32);
    const float linv = 1.0f / lsum;
    if (pass == 0 && (tid & 63) < 16)
        c_pos[bh * NS + sq] = mq * csum * linv;

    float ss = 0.f;
    #pragma unroll
    for (int dt = 0; dt < 16; ++dt) {
        #pragma unroll
        for (int r = 0; r < 4; ++r) {
            const int d = dt * 16 + 4 * g + r;
            const float o = accO[dt][r] * linv;
            const float f = fq[d * NS + sq];
            const float diff = mq * (f - o) + 1e-6f;
            ss += diff * diff;
            if (pass == 0)
                out_recon[((size_t)b * NF + (size_t)h * ND + d) * NS + sq] = f + mq * (o - f);
        }
    }
    ss += __shfl_xor(ss, 16); ss += __shfl_xor(ss, 32);
    if ((tid & 63) < 16) {
        float* dst = (pass == 0) ? ap_part : an_part;
        dst[bh * NS + sq] = ss;
    }
}

// ================= shared tail kernels =================

__global__ __launch_bounds__(256) void comask_kernel(
        const float* __restrict__ c_pos, float* __restrict__ comask) {
    const int b = blockIdx.x;
    const int tid = threadIdx.x;
    __shared__ float smn[256], smx[256];
    const int s1 = tid, s2 = tid + 256;
    float c1 = 0.f, c2 = 0.f;
    for (int h = 0; h < NH; ++h) {
        const float v = c_pos[(b * NH + h) * NS + s1];
        c1 += v * v;
        if (s2 < NS) { const float w = c_pos[(b * NH + h) * NS + s2]; c2 += w * w; }
    }
    c1 = sqrtf(c1);
    float lmn = c1, lmx = c1;
    if (s2 < NS) { c2 = sqrtf(c2); lmn = fminf(lmn, c2); lmx = fmaxf(lmx, c2); }
    smn[tid] = lmn; smx[tid] = lmx;
    __syncthreads();
    for (int off = 128; off > 0; off >>= 1) {
        if (tid < off) {
            smn[tid] = fminf(smn[tid], smn[tid + off]);
            smx[tid] = fmaxf(smx[tid], smx[tid + off]);
        }
        __syncthreads();
    }
    const float mn = smn[0];
    const float inv = 1.0f / (smx[0] - mn + 1e-12f);
    comask[b * NS + s1] = (c1 - mn) * inv;
    if (s2 < NS) comask[b * NS + s2] = (c2 - mn) * inv;
}

__global__ __launch_bounds__(64) void loss_partial(
        const float* __restrict__ comask, const float* __restrict__ ap_part,
        const float* __restrict__ an_part, float* __restrict__ prod) {
    const int s = blockIdx.x;
    const int bb = threadIdx.x;
    float sap = 0.f, san = 0.f;
    for (int hh = 0; hh < NH; ++hh) {
        sap += ap_part[(bb * NH + hh) * NS + s];
        san += an_part[(bb * NH + hh) * NS + s];
    }
    float trip = fmaxf(sqrtf(sap) - sqrtf(san) + 0.3f, 0.0f);
    float cm = comask[bb * NS + s];
    #pragma unroll
    for (int off = 32; off > 0; off >>= 1) {
        trip += __shfl_xor(trip, off);
        cm   += __shfl_xor(cm, off);
    }
    if (bb == 0) prod[s] = trip * cm;
}

__global__ __launch_bounds__(64) void loss_final(
        const float* __restrict__ prod, float* __restrict__ out_loss) {
    const int tid = threadIdx.x;
    float sum = 0.f;
    for (int i = tid; i < NS; i += 64) sum += prod[i];
    #pragma unroll
    for (int off = 32; off > 0; off >>= 1) sum += __shfl_xor(sum, off);
    if (tid == 0) out_loss[0] = sum * (1.0f / ((float)NB * (float)NB * (float)NS));
}

extern "C" void kernel_launch(void* const* d_in, const int* in_sizes, int n_in,
                              void* d_out, int out_size, void* d_ws, size_t ws_size,
                              hipStream_t stream) {
    const float* fv = (const float*)d_in[0];
    const float* ft = (const float*)d_in[1];
    const int* pos  = (const int*)d_in[2];
    const int* neg  = (const int*)d_in[3];
    float* out = (float*)d_out;
    float* ws  = (float*)d_ws;

    float* normArr = ws + WS_NORM;
    float* maskArr = ws + WS_MASK;
    float* c_pos   = ws + WS_CPOS;
    float* comask  = ws + WS_COMASK;
    float* ap      = ws + WS_AP;
    float* an      = ws + WS_AN;
    float* prod    = ws + WS_PROD;

    const size_t need = WS_BF_OFF + 2 * BF_ONE;
    if (ws_size >= need) {
        unsigned short* featKT = (unsigned short*)((char*)d_ws + WS_BF_OFF);
        unsigned short* featKN = (unsigned short*)((char*)d_ws + WS_BF_OFF + BF_ONE);
        convKN_norm_mask<<<dim3(NB * NH), dim3(256), 0, stream>>>(fv, ft, normArr, maskArr, featKN);
        convKT<<<dim3(9, NB * NH), dim3(256), 0, stream>>>(fv, ft, featKT);
        attn_fast<<<dim3(3, NB * NH, 2), dim3(384), 0, stream>>>(
            featKT, featKN, fv, ft, pos, neg, normArr, maskArr, out, c_pos, ap, an);
    } else {
        norm_mask_kernel<<<dim3(NB * NH), dim3(256), 0, stream>>>(fv, ft, normArr, maskArr);
        attn_kernel<<<dim3(3, NB * NH, 2), dim3(384), 0, stream>>>(
            fv, ft, pos, neg, normArr, maskArr, out, c_pos, ap, an);
    }
    comask_kernel<<<dim3(NB), dim3(256), 0, stream>>>(c_pos, comask);
    loss_partial<<<dim3(NS), dim3(64), 0, stream>>>(comask, ap, an, prod);
    loss_final<<<dim3(1), dim3(64), 0, stream>>>(prod, out + RECON_ELEMS);
}